// Round 13
// baseline (1069.185 us; speedup 1.0000x reference)
//
#include <hip/hip_runtime.h>
#include <math.h>

#define G_   8
#define NPG_ 4096
#define HC_  16
#define LAT_ 64
#define FF_  512
#define EDIM_ 3
#define EH_  64
#define NN_  32768
#define EE_  393216

// ---------------- front-end ----------------
__global__ void k_front1(const float* __restrict__ x, const float* __restrict__ w,
                         const float* __restrict__ b, float* __restrict__ h1) {
  int c = blockIdx.x * blockDim.x + threadIdx.x;
  if (c >= FF_) return;
  float acc[G_];
#pragma unroll
  for (int g = 0; g < G_; g++) acc[g] = 0.f;
  for (int r = 0; r < LAT_; r++) {
    float wv = w[r * FF_ + c];
#pragma unroll
    for (int g = 0; g < G_; g++) acc[g] = fmaf(x[g * LAT_ + r], wv, acc[g]);
  }
#pragma unroll
  for (int g = 0; g < G_; g++) h1[g * FF_ + c] = acc[g] + b[c];
}

__global__ __launch_bounds__(512) void k_front2(const float* __restrict__ h1,
                                                const float* __restrict__ w,
                                                const float* __restrict__ b,
                                                float* __restrict__ hn) {
  __shared__ float sh[G_ * FF_];
  for (int i = threadIdx.x; i < G_ * FF_; i += blockDim.x) sh[i] = h1[i];
  __syncthreads();
  int g = threadIdx.x >> 6;
  int lane = threadIdx.x & 63;
  int c = blockIdx.x * 64 + lane;
  const float* shg = &sh[g * FF_];
  float acc = 0.f;
#pragma unroll 8
  for (int r = 0; r < FF_; r++) acc = fmaf(shg[r], w[r * (NPG_ * HC_) + c], acc);
  float v = acc + b[c];
  hn[g * (NPG_ * HC_) + c] = v > 0.f ? v : expm1f(v);
}

// ---------------- counting sort by src ----------------
__global__ void k_zero(int* __restrict__ p, int nv) {
  int i = blockIdx.x * blockDim.x + threadIdx.x;
  if (i < nv) p[i] = 0;
}
__global__ void k_hist(const int* __restrict__ key, int* __restrict__ cnt) {
  int e = blockIdx.x * blockDim.x + threadIdx.x;
  if (e < EE_) atomicAdd(&cnt[key[e]], 1);
}
__global__ __launch_bounds__(1024) void k_scan(const int* __restrict__ cnt,
                                               int* __restrict__ rowptr,
                                               int* __restrict__ cursor) {
  __shared__ int part[1024];
  int t = threadIdx.x;
  int base = t * 32;
  int loc[32];
  int s = 0;
#pragma unroll
  for (int i = 0; i < 32; i++) { loc[i] = s; s += cnt[base + i]; }
  part[t] = s;
  __syncthreads();
  for (int off = 1; off < 1024; off <<= 1) {
    int v = (t >= off) ? part[t - off] : 0;
    __syncthreads();
    part[t] += v;
    __syncthreads();
  }
  int pre = (t == 0) ? 0 : part[t - 1];
#pragma unroll
  for (int i = 0; i < 32; i++) {
    int v = pre + loc[i];
    rowptr[base + i] = v;
    cursor[base + i] = v;
  }
  if (t == 1023) rowptr[NN_] = part[1023];
}
// fused scatter: place edge attrs+dst AND src node id at the src-sorted slot
__global__ void k_scatter(const int* __restrict__ src, const int* __restrict__ dst,
                          const float* __restrict__ ea, int* __restrict__ cursor,
                          float4* __restrict__ eas4, int* __restrict__ srcn) {
  int e = blockIdx.x * blockDim.x + threadIdx.x;
  if (e >= EE_) return;
  int sn = src[e];
  int pos = atomicAdd(&cursor[sn], 1);
  eas4[pos] = make_float4(ea[e * 3], ea[e * 3 + 1], ea[e * 3 + 2],
                          __int_as_float(dst[e]));
  srcn[pos] = sn;
}

// ---------------- per-conv kernels ----------------
__global__ void k_nodeinit(const float* __restrict__ hn, const float* __restrict__ root,
                           const float* __restrict__ bias, float* __restrict__ out) {
  int idx = blockIdx.x * blockDim.x + threadIdx.x;
  if (idx >= NN_ * HC_) return;
  int nd = idx >> 4, o = idx & 15;
  float acc = bias[o];
#pragma unroll
  for (int i = 0; i < 16; i++) acc = fmaf(hn[nd * 16 + i], root[i * 16 + o], acc);
  out[idx] = acc;
}

// W2m h-major: W2m[i*1024 + h*16 + o] = w2[h*256 + i*16 + o]
// w1p4[h] = (w1[0][h], w1[1][h], w1[2][h], b1[h])
__global__ void k_wprep(const float* __restrict__ w2, const float* __restrict__ w1,
                        const float* __restrict__ b1, float* __restrict__ W2m,
                        float4* __restrict__ w1p4) {
  int idx = blockIdx.x * 256 + threadIdx.x;
  if (idx < 16384) {
    int i = idx >> 10;
    int h = (idx >> 4) & 63;
    int o = idx & 15;
    W2m[idx] = w2[h * 256 + i * 16 + o];
  }
  if (idx < 64) {
    w1p4[idx] = make_float4(w1[idx], w1[64 + idx], w1[128 + idx], b1[idx]);
  }
}

// Per-node message operators, [n][h][o] layout. Lane l = h, 2 nodes/wave.
// Mbuf4[n*256 + h*4 + c] = M_n[h][o=c*4..c*4+3] = sum_i x_n[i]*W2m[i][h][...]
// Also Tbuf[n*16+o] = sum_i x_n[i]*b2[i*16+o]  (lanes 0..31).
__global__ __launch_bounds__(256, 4) void k_precM(
    const float* __restrict__ hn, const float* __restrict__ W2m,
    const float* __restrict__ b2, float4* __restrict__ Mbuf4,
    float* __restrict__ Tbuf) {
  int tid = threadIdx.x;
  int wave = tid >> 6, l = tid & 63;
  int n0 = (blockIdx.x * 4 + wave) * 2;
  const float4* __restrict__ W2m4 = (const float4*)W2m;

  float4 A0 = {0,0,0,0}, A1 = {0,0,0,0}, A2 = {0,0,0,0}, A3 = {0,0,0,0};
  float4 B0 = {0,0,0,0}, B1 = {0,0,0,0}, B2 = {0,0,0,0}, B3 = {0,0,0,0};
  for (int i = 0; i < 16; i++) {
    float xA = hn[n0 * 16 + i];
    float xB = hn[n0 * 16 + 16 + i];
    float4 w0 = W2m4[i * 256 + l * 4 + 0];
    float4 w1v = W2m4[i * 256 + l * 4 + 1];
    float4 w2v = W2m4[i * 256 + l * 4 + 2];
    float4 w3v = W2m4[i * 256 + l * 4 + 3];
    A0.x = fmaf(xA, w0.x, A0.x); A0.y = fmaf(xA, w0.y, A0.y);
    A0.z = fmaf(xA, w0.z, A0.z); A0.w = fmaf(xA, w0.w, A0.w);
    A1.x = fmaf(xA, w1v.x, A1.x); A1.y = fmaf(xA, w1v.y, A1.y);
    A1.z = fmaf(xA, w1v.z, A1.z); A1.w = fmaf(xA, w1v.w, A1.w);
    A2.x = fmaf(xA, w2v.x, A2.x); A2.y = fmaf(xA, w2v.y, A2.y);
    A2.z = fmaf(xA, w2v.z, A2.z); A2.w = fmaf(xA, w2v.w, A2.w);
    A3.x = fmaf(xA, w3v.x, A3.x); A3.y = fmaf(xA, w3v.y, A3.y);
    A3.z = fmaf(xA, w3v.z, A3.z); A3.w = fmaf(xA, w3v.w, A3.w);
    B0.x = fmaf(xB, w0.x, B0.x); B0.y = fmaf(xB, w0.y, B0.y);
    B0.z = fmaf(xB, w0.z, B0.z); B0.w = fmaf(xB, w0.w, B0.w);
    B1.x = fmaf(xB, w1v.x, B1.x); B1.y = fmaf(xB, w1v.y, B1.y);
    B1.z = fmaf(xB, w1v.z, B1.z); B1.w = fmaf(xB, w1v.w, B1.w);
    B2.x = fmaf(xB, w2v.x, B2.x); B2.y = fmaf(xB, w2v.y, B2.y);
    B2.z = fmaf(xB, w2v.z, B2.z); B2.w = fmaf(xB, w2v.w, B2.w);
    B3.x = fmaf(xB, w3v.x, B3.x); B3.y = fmaf(xB, w3v.y, B3.y);
    B3.z = fmaf(xB, w3v.z, B3.z); B3.w = fmaf(xB, w3v.w, B3.w);
  }
  int s0 = n0 * 256 + l * 4;
  Mbuf4[s0 + 0] = A0; Mbuf4[s0 + 1] = A1; Mbuf4[s0 + 2] = A2; Mbuf4[s0 + 3] = A3;
  Mbuf4[s0 + 256 + 0] = B0; Mbuf4[s0 + 256 + 1] = B1;
  Mbuf4[s0 + 256 + 2] = B2; Mbuf4[s0 + 256 + 3] = B3;

  if (l < 32) {
    int nn = n0 + (l >> 4);
    int o = l & 15;
    float t = 0.f;
#pragma unroll
    for (int i = 0; i < 16; i++) t = fmaf(hn[nn * 16 + i], b2[i * 16 + o], t);
    Tbuf[nn * 16 + o] = t;
  }
}

// Edge aggregation: ONE LANE = ONE EDGE. 64 consecutive src-sorted edges per
// wave (E % 64 == 0 -> no bounds checks). Per lane: h-loop with w1p4[h] via
// wave-uniform s_load (SGPR operands), hidden once (4 VALU), 16 fma against
// M[ni][h][*] (lanes sharing a src node broadcast from L1). 16 atomics/edge.
__global__ __launch_bounds__(256, 4) void k_edge(
    const int* __restrict__ srcn, const float4* __restrict__ eas4,
    const float4* __restrict__ w1p4, const float4* __restrict__ Mbuf4,
    const float4* __restrict__ Tbuf4, float* __restrict__ hnext) {
  int tid = threadIdx.x;
  int e = (blockIdx.x * 4 + (tid >> 6)) * 64 + (tid & 63);

  float4 ea = eas4[e];
  int ni = srcn[e];
  int d = __float_as_int(ea.w);
  const float4* __restrict__ Mb = &Mbuf4[ni * 256];
  const float4* __restrict__ Tb = &Tbuf4[ni * 4];
  float4 p0 = Tb[0], p1 = Tb[1], p2 = Tb[2], p3 = Tb[3];

#pragma unroll 2
  for (int h = 0; h < 64; h++) {
    float4 wv = w1p4[h];  // uniform address -> scalar load
    float hd = fmaf(ea.z, wv.z, fmaf(ea.y, wv.y, fmaf(ea.x, wv.x, wv.w)));
    hd = fmaxf(hd, 0.f);
    float4 m0 = Mb[h * 4 + 0];
    float4 m1 = Mb[h * 4 + 1];
    float4 m2 = Mb[h * 4 + 2];
    float4 m3 = Mb[h * 4 + 3];
    p0.x = fmaf(hd, m0.x, p0.x); p0.y = fmaf(hd, m0.y, p0.y);
    p0.z = fmaf(hd, m0.z, p0.z); p0.w = fmaf(hd, m0.w, p0.w);
    p1.x = fmaf(hd, m1.x, p1.x); p1.y = fmaf(hd, m1.y, p1.y);
    p1.z = fmaf(hd, m1.z, p1.z); p1.w = fmaf(hd, m1.w, p1.w);
    p2.x = fmaf(hd, m2.x, p2.x); p2.y = fmaf(hd, m2.y, p2.y);
    p2.z = fmaf(hd, m2.z, p2.z); p2.w = fmaf(hd, m2.w, p2.w);
    p3.x = fmaf(hd, m3.x, p3.x); p3.y = fmaf(hd, m3.y, p3.y);
    p3.z = fmaf(hd, m3.z, p3.z); p3.w = fmaf(hd, m3.w, p3.w);
  }

  float* __restrict__ row = &hnext[d * 16];
  atomicAdd(row + 0,  p0.x); atomicAdd(row + 1,  p0.y);
  atomicAdd(row + 2,  p0.z); atomicAdd(row + 3,  p0.w);
  atomicAdd(row + 4,  p1.x); atomicAdd(row + 5,  p1.y);
  atomicAdd(row + 6,  p1.z); atomicAdd(row + 7,  p1.w);
  atomicAdd(row + 8,  p2.x); atomicAdd(row + 9,  p2.y);
  atomicAdd(row + 10, p2.z); atomicAdd(row + 11, p2.w);
  atomicAdd(row + 12, p3.x); atomicAdd(row + 13, p3.y);
  atomicAdd(row + 14, p3.z); atomicAdd(row + 15, p3.w);
}

__global__ void k_elu(const float* __restrict__ in, float* __restrict__ out) {
  int idx = blockIdx.x * blockDim.x + threadIdx.x;
  if (idx >= NN_ * HC_) return;
  float v = in[idx];
  out[idx] = v > 0.f ? v : expm1f(v);
}

// ---------------- launch ----------------
extern "C" void kernel_launch(void* const* d_in, const int* in_sizes, int n_in,
                              void* d_out, int out_size, void* d_ws, size_t ws_size,
                              hipStream_t stream) {
  const float* x    = (const float*)d_in[0];
  const int*   ei   = (const int*)d_in[1];
  const float* ea   = (const float*)d_in[2];
  const float* fc2w = (const float*)d_in[3];
  const float* fc2b = (const float*)d_in[4];
  const float* fc1w = (const float*)d_in[5];
  const float* fc1b = (const float*)d_in[6];
  float* out = (float*)d_out;

  float* ws = (float*)d_ws;
  float*  h1     = ws;                               // 4096
  float*  hnode  = h1 + 4096;                        // N*16
  float*  hnext  = hnode + (size_t)NN_ * HC_;        // N*16
  float*  W2m    = hnext + (size_t)NN_ * HC_;        // 16384
  float4* w1p4   = (float4*)(W2m + 16384);           // 256 floats
  float4* eas4   = (float4*)((float*)w1p4 + 256);    // (E+8)*4 floats
  float4* Mbuf4  = (float4*)((float*)eas4 + (size_t)(EE_ + 8) * 4);  // N*1024
  float*  Tbuf   = (float*)Mbuf4 + (size_t)NN_ * 1024;               // N*16
  int*    srcn   = (int*)(Tbuf + (size_t)NN_ * HC_); // E
  int*    cnt    = srcn + EE_;                       // N
  int*    rowptr = cnt + NN_;                        // N+1
  int*    cursor = rowptr + NN_ + 1;                 // N

  const int* src  = ei;
  const int* dstp = ei + EE_;

  k_front1<<<2, 256, 0, stream>>>(x, fc2w, fc2b, h1);
  k_front2<<<1024, 512, 0, stream>>>(h1, fc1w, fc1b, hnode);

  k_zero<<<(NN_ + 255) / 256, 256, 0, stream>>>(cnt, NN_);
  k_hist<<<(EE_ + 255) / 256, 256, 0, stream>>>(src, cnt);
  k_scan<<<1, 1024, 0, stream>>>(cnt, rowptr, cursor);
  k_scatter<<<(EE_ + 255) / 256, 256, 0, stream>>>(src, dstp, ea, cursor,
                                                   eas4, srcn);

  for (int cv = 0; cv < 2; cv++) {
    const float* root = (const float*)d_in[7 + cv * 6];
    const float* cb   = (const float*)d_in[8 + cv * 6];
    const float* w1   = (const float*)d_in[9 + cv * 6];
    const float* b1   = (const float*)d_in[10 + cv * 6];
    const float* w2   = (const float*)d_in[11 + cv * 6];
    const float* b2   = (const float*)d_in[12 + cv * 6];
    k_wprep<<<64, 256, 0, stream>>>(w2, w1, b1, W2m, w1p4);
    k_nodeinit<<<NN_ * HC_ / 256, 256, 0, stream>>>(hnode, root, cb, hnext);
    k_precM<<<NN_ / 8, 256, 0, stream>>>(hnode, W2m, b2, Mbuf4, Tbuf);
    k_edge<<<EE_ / 256, 256, 0, stream>>>(srcn, eas4, w1p4, Mbuf4,
                                          (const float4*)Tbuf, hnext);
    k_elu<<<NN_ * HC_ / 256, 256, 0, stream>>>(hnext, cv == 0 ? hnode : out);
  }
}

// Round 15
// 673.291 us; speedup vs baseline: 1.5880x; 1.5880x over previous
//
#include <hip/hip_runtime.h>
#include <math.h>

#define G_   8
#define NPG_ 4096
#define HC_  16
#define LAT_ 64
#define FF_  512
#define EDIM_ 3
#define EH_  64
#define NN_  32768
#define EE_  393216
#define EPAD_ (EE_ + NN_ + 32)  // padded edge slots + prefetch slack

typedef float v2f __attribute__((ext_vector_type(2)));

// v_pk_fma_f32: all sources are 64-bit VGPR pairs; scalar broadcast is done
// with op_sel word-selection from a pair (no 32-bit operands - R14 lesson).
// H0: d = a * lo(b) + hi(c)     (x-term + bias init)
#define PK_H0(d, a, b, c)                                                   \
  asm("v_pk_fma_f32 %0, %1, %2, %3 op_sel:[0,0,1] op_sel_hi:[1,0,1]"        \
      : "=v"(d) : "v"(a), "v"(b), "v"(c))
// BH: d += a * hi(b)
#define PK_BH(d, a, b)                                                      \
  asm("v_pk_fma_f32 %0, %1, %2, %0 op_sel:[0,1,0] op_sel_hi:[1,1,1]"        \
      : "+v"(d) : "v"(a), "v"(b))
// BL: d += a * lo(b)
#define PK_BL(d, a, b)                                                      \
  asm("v_pk_fma_f32 %0, %1, %2, %0 op_sel:[0,0,0] op_sel_hi:[1,0,1]"        \
      : "+v"(d) : "v"(a), "v"(b))

// ---------------- front-end ----------------
__global__ void k_front1(const float* __restrict__ x, const float* __restrict__ w,
                         const float* __restrict__ b, float* __restrict__ h1) {
  int c = blockIdx.x * blockDim.x + threadIdx.x;
  if (c >= FF_) return;
  float acc[G_];
#pragma unroll
  for (int g = 0; g < G_; g++) acc[g] = 0.f;
  for (int r = 0; r < LAT_; r++) {
    float wv = w[r * FF_ + c];
#pragma unroll
    for (int g = 0; g < G_; g++) acc[g] = fmaf(x[g * LAT_ + r], wv, acc[g]);
  }
#pragma unroll
  for (int g = 0; g < G_; g++) h1[g * FF_ + c] = acc[g] + b[c];
}

__global__ __launch_bounds__(512) void k_front2(const float* __restrict__ h1,
                                                const float* __restrict__ w,
                                                const float* __restrict__ b,
                                                float* __restrict__ hn) {
  __shared__ float sh[G_ * FF_];
  for (int i = threadIdx.x; i < G_ * FF_; i += blockDim.x) sh[i] = h1[i];
  __syncthreads();
  int g = threadIdx.x >> 6;
  int lane = threadIdx.x & 63;
  int c = blockIdx.x * 64 + lane;
  const float* shg = &sh[g * FF_];
  float acc = 0.f;
#pragma unroll 8
  for (int r = 0; r < FF_; r++) acc = fmaf(shg[r], w[r * (NPG_ * HC_) + c], acc);
  float v = acc + b[c];
  hn[g * (NPG_ * HC_) + c] = v > 0.f ? v : expm1f(v);
}

// ---------------- counting sort by src (ranges padded to even) -------------
__global__ void k_zero(int* __restrict__ p, int nv) {
  int i = blockIdx.x * blockDim.x + threadIdx.x;
  if (i < nv) p[i] = 0;
}
__global__ void k_hist(const int* __restrict__ key, int* __restrict__ cnt) {
  int e = blockIdx.x * blockDim.x + threadIdx.x;
  if (e < EE_) atomicAdd(&cnt[key[e]], 1);
}
__global__ __launch_bounds__(1024) void k_scan(const int* __restrict__ cnt,
                                               int* __restrict__ rowptr,
                                               int* __restrict__ cursor) {
  __shared__ int part[1024];
  int t = threadIdx.x;
  int base = t * 32;
  int loc[32];
  int s = 0;
#pragma unroll
  for (int i = 0; i < 32; i++) {
    loc[i] = s;
    s += (cnt[base + i] + 1) & ~1;
  }
  part[t] = s;
  __syncthreads();
  for (int off = 1; off < 1024; off <<= 1) {
    int v = (t >= off) ? part[t - off] : 0;
    __syncthreads();
    part[t] += v;
    __syncthreads();
  }
  int pre = (t == 0) ? 0 : part[t - 1];
#pragma unroll
  for (int i = 0; i < 32; i++) {
    int v = pre + loc[i];
    rowptr[base + i] = v;
    cursor[base + i] = v;
  }
  if (t == 1023) rowptr[NN_] = part[1023];
}
// prefill pair records with zero-attr edges aimed at dummy row NN_
__global__ void k_pfill(float4* __restrict__ pairb) {
  int p = blockIdx.x * blockDim.x + threadIdx.x;
  if (p >= EPAD_ / 2) return;
  float df = __int_as_float(NN_);
  pairb[p * 2]     = make_float4(0.f, 0.f, 0.f, 0.f);
  pairb[p * 2 + 1] = make_float4(0.f, 0.f, df, df);
}
// scatter edge attrs into padded src-sorted pair records:
// pair p floats [p*8..p*8+7] = {x0,x1,y0,y1,z0,z1,d0,d1}; edge slot s=pos&1
__global__ void k_scatter(const int* __restrict__ src, const int* __restrict__ dst,
                          const float* __restrict__ ea, int* __restrict__ cursor,
                          float* __restrict__ pairb) {
  int e = blockIdx.x * blockDim.x + threadIdx.x;
  if (e >= EE_) return;
  int pos = atomicAdd(&cursor[src[e]], 1);
  int b = (pos >> 1) * 8 + (pos & 1);
  pairb[b]     = ea[e * 3];
  pairb[b + 2] = ea[e * 3 + 1];
  pairb[b + 4] = ea[e * 3 + 2];
  pairb[b + 6] = __int_as_float(dst[e]);
}

// ---------------- per-conv kernels ----------------
__global__ void k_nodeinit(const float* __restrict__ hn, const float* __restrict__ root,
                           const float* __restrict__ bias, float* __restrict__ out) {
  int idx = blockIdx.x * blockDim.x + threadIdx.x;
  if (idx >= NN_ * HC_) return;
  int nd = idx >> 4, o = idx & 15;
  float acc = bias[o];
#pragma unroll
  for (int i = 0; i < 16; i++) acc = fmaf(hn[nd * 16 + i], root[i * 16 + o], acc);
  out[idx] = acc;
}

// W2m lane-fast: W2m[i*1024 + j4*256 + l*4 + c] = w2[h*256 + i*16 + o],
//   h=(l>>4)*16 + j4*4 + c, o=l&15.  w1p4[h] = (w1[0..2][h], b1[h])
__global__ void k_wprep(const float* __restrict__ w2, const float* __restrict__ w1,
                        const float* __restrict__ b1, float* __restrict__ W2m,
                        float4* __restrict__ w1p4) {
  int idx = blockIdx.x * 256 + threadIdx.x;
  if (idx < 16384) {
    int i  = idx >> 10;
    int j4 = (idx >> 8) & 3;
    int l  = (idx >> 2) & 63;
    int c  = idx & 3;
    int q = l >> 4, o = l & 15;
    int h = q * 16 + j4 * 4 + c;
    W2m[idx] = w2[h * 256 + i * 16 + o];
  }
  if (idx < 64) {
    w1p4[idx] = make_float4(w1[idx], w1[64 + idx], w1[128 + idx], b1[idx]);
  }
}

// Precompute per-node message matrices (proven R9/R12 form):
// Mbuf[n*1024 + j4*256 + l*4 + c] = sum_i x_n[i]*W2m[i*1024 + j4*256 + l*4 + c]
__global__ __launch_bounds__(256, 4) void k_precM(
    const float* __restrict__ hn, const float* __restrict__ W2m,
    float4* __restrict__ Mbuf4) {
  int tid = threadIdx.x;
  int wave = tid >> 6, l = tid & 63;
  int n0 = (blockIdx.x * 4 + wave) * 4;
  const float4* __restrict__ W2m4 = (const float4*)W2m;

  float4 a0[4], a1[4], a2[4], a3[4];
#pragma unroll
  for (int j4 = 0; j4 < 4; j4++) {
    a0[j4] = make_float4(0.f, 0.f, 0.f, 0.f);
    a1[j4] = make_float4(0.f, 0.f, 0.f, 0.f);
    a2[j4] = make_float4(0.f, 0.f, 0.f, 0.f);
    a3[j4] = make_float4(0.f, 0.f, 0.f, 0.f);
  }
  for (int i = 0; i < 16; i++) {
    float x0 = hn[(n0 + 0) * 16 + i];
    float x1 = hn[(n0 + 1) * 16 + i];
    float x2 = hn[(n0 + 2) * 16 + i];
    float x3 = hn[(n0 + 3) * 16 + i];
#pragma unroll
    for (int j4 = 0; j4 < 4; j4++) {
      float4 w = W2m4[i * 256 + j4 * 64 + l];
      a0[j4].x = fmaf(x0, w.x, a0[j4].x); a0[j4].y = fmaf(x0, w.y, a0[j4].y);
      a0[j4].z = fmaf(x0, w.z, a0[j4].z); a0[j4].w = fmaf(x0, w.w, a0[j4].w);
      a1[j4].x = fmaf(x1, w.x, a1[j4].x); a1[j4].y = fmaf(x1, w.y, a1[j4].y);
      a1[j4].z = fmaf(x1, w.z, a1[j4].z); a1[j4].w = fmaf(x1, w.w, a1[j4].w);
      a2[j4].x = fmaf(x2, w.x, a2[j4].x); a2[j4].y = fmaf(x2, w.y, a2[j4].y);
      a2[j4].z = fmaf(x2, w.z, a2[j4].z); a2[j4].w = fmaf(x2, w.w, a2[j4].w);
      a3[j4].x = fmaf(x3, w.x, a3[j4].x); a3[j4].y = fmaf(x3, w.y, a3[j4].y);
      a3[j4].z = fmaf(x3, w.z, a3[j4].z); a3[j4].w = fmaf(x3, w.w, a3[j4].w);
    }
  }
  int s0 = n0 * 256;
#pragma unroll
  for (int j4 = 0; j4 < 4; j4++) Mbuf4[s0 + j4 * 64 + l] = a0[j4];
#pragma unroll
  for (int j4 = 0; j4 < 4; j4++) Mbuf4[s0 + 256 + j4 * 64 + l] = a1[j4];
#pragma unroll
  for (int j4 = 0; j4 < 4; j4++) Mbuf4[s0 + 512 + j4 * 64 + l] = a2[j4];
#pragma unroll
  for (int j4 = 0; j4 < 4; j4++) Mbuf4[s0 + 768 + j4 * 64 + l] = a3[j4];
}

// Edge aggregation. One wave per source node; w1 in LDS as v2f pairs;
// 8 edges per chunk in 4 pair-groups; hidden+accumulate via v_pk_fma_f32
// with op_sel broadcasts; ReLU as 2 scalar v_max on the pair halves.
__global__ __launch_bounds__(256, 4) void k_edge(
    const float* __restrict__ hn, const int* __restrict__ rowptr,
    const v2f* __restrict__ pv, const float4* __restrict__ w1p4,
    const float* __restrict__ b2, const float4* __restrict__ Mbuf4,
    float* __restrict__ hnext) {
  __shared__ float sw1[512];
  int tid = threadIdx.x;
  if (tid < 128) ((v2f*)sw1)[tid] = ((const v2f*)w1p4)[tid];
  __syncthreads();

  int wave = tid >> 6, l = tid & 63;
  int o = l & 15, q = l >> 4;
  int n = blockIdx.x * 4 + wave;

  int rs = rowptr[n], re = rowptr[n + 1];  // even-padded range
  if (rs >= re) return;

  // M pairs: mv[j>>1] holds {M[2jp], M[2jp+1]} for this lane
  int mb = n * 256 + l;
  const v2f* __restrict__ Mv = (const v2f*)Mbuf4;
  v2f mv[8];
  mv[0] = Mv[mb * 2];          mv[1] = Mv[mb * 2 + 1];
  mv[2] = Mv[(mb + 64) * 2];   mv[3] = Mv[(mb + 64) * 2 + 1];
  mv[4] = Mv[(mb + 128) * 2];  mv[5] = Mv[(mb + 128) * 2 + 1];
  mv[6] = Mv[(mb + 192) * 2];  mv[7] = Mv[(mb + 192) * 2 + 1];

  const float4* __restrict__ hx4 = (const float4*)&hn[n * 16];
  float T = 0.f;
#pragma unroll
  for (int i4 = 0; i4 < 4; i4++) {
    float4 xq = hx4[i4];
    T = fmaf(xq.x, b2[(i4 * 4 + 0) * 16 + o], T);
    T = fmaf(xq.y, b2[(i4 * 4 + 1) * 16 + o], T);
    T = fmaf(xq.z, b2[(i4 * 4 + 2) * 16 + o], T);
    T = fmaf(xq.w, b2[(i4 * 4 + 3) * 16 + o], T);
  }

  const v2f* __restrict__ w1v = (const v2f*)sw1 + q * 32;  // pairs for h=q*16+j

  int b0 = rs * 2;
  v2f cXa = pv[b0 + 0],  cYa = pv[b0 + 1],  cZa = pv[b0 + 2],  cDa = pv[b0 + 3];
  v2f cXb = pv[b0 + 4],  cYb = pv[b0 + 5],  cZb = pv[b0 + 6],  cDb = pv[b0 + 7];
  v2f cXc = pv[b0 + 8],  cYc = pv[b0 + 9],  cZc = pv[b0 + 10], cDc = pv[b0 + 11];
  v2f cXd = pv[b0 + 12], cYd = pv[b0 + 13], cZd = pv[b0 + 14], cDd = pv[b0 + 15];

  for (int k = rs; k < re; k += 8) {
    int nb = (k + 8) * 2;
    v2f nXa = pv[nb + 0],  nYa = pv[nb + 1],  nZa = pv[nb + 2],  nDa = pv[nb + 3];
    v2f nXb = pv[nb + 4],  nYb = pv[nb + 5],  nZb = pv[nb + 6],  nDb = pv[nb + 7];
    v2f nXc = pv[nb + 8],  nYc = pv[nb + 9],  nZc = pv[nb + 10], nDc = pv[nb + 11];
    v2f nXd = pv[nb + 12], nYd = pv[nb + 13], nZd = pv[nb + 14], nDd = pv[nb + 15];

    v2f pA; pA.x = 0.f; pA.y = 0.f;
    v2f pB = pA, pC = pA, pD = pA;
#pragma unroll
    for (int j = 0; j < 16; j++) {
      v2f wxy = w1v[j * 2];
      v2f wzb = w1v[j * 2 + 1];
      v2f mj = mv[j >> 1];
      v2f hA, hB, hC, hD;
      PK_H0(hA, cXa, wxy, wzb); PK_BH(hA, cYa, wxy); PK_BL(hA, cZa, wzb);
      PK_H0(hB, cXb, wxy, wzb); PK_BH(hB, cYb, wxy); PK_BL(hB, cZb, wzb);
      PK_H0(hC, cXc, wxy, wzb); PK_BH(hC, cYc, wxy); PK_BL(hC, cZc, wzb);
      PK_H0(hD, cXd, wxy, wzb); PK_BH(hD, cYd, wxy); PK_BL(hD, cZd, wzb);
      hA.x = fmaxf(hA.x, 0.f); hA.y = fmaxf(hA.y, 0.f);
      hB.x = fmaxf(hB.x, 0.f); hB.y = fmaxf(hB.y, 0.f);
      hC.x = fmaxf(hC.x, 0.f); hC.y = fmaxf(hC.y, 0.f);
      hD.x = fmaxf(hD.x, 0.f); hD.y = fmaxf(hD.y, 0.f);
      if (j & 1) {
        PK_BH(pA, hA, mj); PK_BH(pB, hB, mj);
        PK_BH(pC, hC, mj); PK_BH(pD, hD, mj);
      } else {
        PK_BL(pA, hA, mj); PK_BL(pB, hB, mj);
        PK_BL(pC, hC, mj); PK_BL(pD, hD, mj);
      }
    }
    float p0 = pA.x, p1 = pA.y, p2 = pB.x, p3 = pB.y;
    float p4 = pC.x, p5 = pC.y, p6 = pD.x, p7 = pD.y;
    p0 += __shfl_xor(p0, 16); p1 += __shfl_xor(p1, 16);
    p2 += __shfl_xor(p2, 16); p3 += __shfl_xor(p3, 16);
    p4 += __shfl_xor(p4, 16); p5 += __shfl_xor(p5, 16);
    p6 += __shfl_xor(p6, 16); p7 += __shfl_xor(p7, 16);
    p0 += __shfl_xor(p0, 32); p1 += __shfl_xor(p1, 32);
    p2 += __shfl_xor(p2, 32); p3 += __shfl_xor(p3, 32);
    p4 += __shfl_xor(p4, 32); p5 += __shfl_xor(p5, 32);
    p6 += __shfl_xor(p6, 32); p7 += __shfl_xor(p7, 32);

    // lane group q commits edges k+2q, k+2q+1 (re even -> one guard covers both)
    float vlo = (q == 0) ? p0 : (q == 1) ? p2 : (q == 2) ? p4 : p6;
    float vhi = (q == 0) ? p1 : (q == 1) ? p3 : (q == 2) ? p5 : p7;
    v2f cDq = (q == 0) ? cDa : (q == 1) ? cDb : (q == 2) ? cDc : cDd;
    if (k + 2 * q < re) {
      atomicAdd(&hnext[__float_as_int(cDq.x) * 16 + o], vlo + T);
      atomicAdd(&hnext[__float_as_int(cDq.y) * 16 + o], vhi + T);
    }

    cXa = nXa; cYa = nYa; cZa = nZa; cDa = nDa;
    cXb = nXb; cYb = nYb; cZb = nZb; cDb = nDb;
    cXc = nXc; cYc = nYc; cZc = nZc; cDc = nDc;
    cXd = nXd; cYd = nYd; cZd = nZd; cDd = nDd;
  }
}

__global__ void k_elu(const float* __restrict__ in, float* __restrict__ out) {
  int idx = blockIdx.x * blockDim.x + threadIdx.x;
  if (idx >= NN_ * HC_) return;
  float v = in[idx];
  out[idx] = v > 0.f ? v : expm1f(v);
}

// ---------------- launch ----------------
extern "C" void kernel_launch(void* const* d_in, const int* in_sizes, int n_in,
                              void* d_out, int out_size, void* d_ws, size_t ws_size,
                              hipStream_t stream) {
  const float* x    = (const float*)d_in[0];
  const int*   ei   = (const int*)d_in[1];
  const float* ea   = (const float*)d_in[2];
  const float* fc2w = (const float*)d_in[3];
  const float* fc2b = (const float*)d_in[4];
  const float* fc1w = (const float*)d_in[5];
  const float* fc1b = (const float*)d_in[6];
  float* out = (float*)d_out;

  float* ws = (float*)d_ws;
  float*  h1     = ws;                                // 4096
  float*  hnode  = h1 + 4096;                         // N*16
  float*  hnext  = hnode + (size_t)NN_ * HC_;         // N*16 + 16 (dummy row)
  float*  W2m    = hnext + (size_t)NN_ * HC_ + 16;    // 16384
  float4* w1p4   = (float4*)(W2m + 16384);            // 256 floats
  float*  pairb  = (float*)w1p4 + 256;                // EPAD_*4 floats
  float4* Mbuf4  = (float4*)(pairb + (size_t)EPAD_ * 4);  // N*1024 floats
  int*    cnt    = (int*)((float*)Mbuf4 + (size_t)NN_ * 1024);
  int*    rowptr = cnt + NN_;
  int*    cursor = rowptr + NN_ + 1;

  const int* src  = ei;
  const int* dstp = ei + EE_;

  k_front1<<<2, 256, 0, stream>>>(x, fc2w, fc2b, h1);
  k_front2<<<1024, 512, 0, stream>>>(h1, fc1w, fc1b, hnode);

  k_zero<<<(NN_ + 255) / 256, 256, 0, stream>>>(cnt, NN_);
  k_hist<<<(EE_ + 255) / 256, 256, 0, stream>>>(src, cnt);
  k_scan<<<1, 1024, 0, stream>>>(cnt, rowptr, cursor);
  k_pfill<<<(EPAD_ / 2 + 255) / 256, 256, 0, stream>>>((float4*)pairb);
  k_scatter<<<(EE_ + 255) / 256, 256, 0, stream>>>(src, dstp, ea, cursor, pairb);

  for (int cv = 0; cv < 2; cv++) {
    const float* root = (const float*)d_in[7 + cv * 6];
    const float* cb   = (const float*)d_in[8 + cv * 6];
    const float* w1   = (const float*)d_in[9 + cv * 6];
    const float* b1   = (const float*)d_in[10 + cv * 6];
    const float* w2   = (const float*)d_in[11 + cv * 6];
    const float* b2   = (const float*)d_in[12 + cv * 6];
    k_wprep<<<64, 256, 0, stream>>>(w2, w1, b1, W2m, w1p4);
    k_nodeinit<<<NN_ * HC_ / 256, 256, 0, stream>>>(hnode, root, cb, hnext);
    k_precM<<<NN_ / 16, 256, 0, stream>>>(hnode, W2m, Mbuf4);
    k_edge<<<NN_ / 4, 256, 0, stream>>>(hnode, rowptr, (const v2f*)pairb, w1p4,
                                        b2, Mbuf4, hnext);
    k_elu<<<NN_ * HC_ / 256, 256, 0, stream>>>(hnext, cv == 0 ? hnode : out);
  }
}

// Round 16
// 547.461 us; speedup vs baseline: 1.9530x; 1.2298x over previous
//
#include <hip/hip_runtime.h>
#include <math.h>

#define G_   8
#define NPG_ 4096
#define HC_  16
#define LAT_ 64
#define FF_  512
#define EDIM_ 3
#define EH_  64
#define NN_  32768
#define EE_  393216

// ---------------- front-end ----------------
__global__ void k_front1(const float* __restrict__ x, const float* __restrict__ w,
                         const float* __restrict__ b, float* __restrict__ h1) {
  int c = blockIdx.x * blockDim.x + threadIdx.x;
  if (c >= FF_) return;
  float acc[G_];
#pragma unroll
  for (int g = 0; g < G_; g++) acc[g] = 0.f;
  for (int r = 0; r < LAT_; r++) {
    float wv = w[r * FF_ + c];
#pragma unroll
    for (int g = 0; g < G_; g++) acc[g] = fmaf(x[g * LAT_ + r], wv, acc[g]);
  }
#pragma unroll
  for (int g = 0; g < G_; g++) h1[g * FF_ + c] = acc[g] + b[c];
}

__global__ __launch_bounds__(512) void k_front2(const float* __restrict__ h1,
                                                const float* __restrict__ w,
                                                const float* __restrict__ b,
                                                float* __restrict__ hn) {
  __shared__ float sh[G_ * FF_];
  for (int i = threadIdx.x; i < G_ * FF_; i += blockDim.x) sh[i] = h1[i];
  __syncthreads();
  int g = threadIdx.x >> 6;
  int lane = threadIdx.x & 63;
  int c = blockIdx.x * 64 + lane;
  const float* shg = &sh[g * FF_];
  float acc = 0.f;
#pragma unroll 8
  for (int r = 0; r < FF_; r++) acc = fmaf(shg[r], w[r * (NPG_ * HC_) + c], acc);
  float v = acc + b[c];
  hn[g * (NPG_ * HC_) + c] = v > 0.f ? v : expm1f(v);
}

// ---------------- counting sort by src ----------------
__global__ void k_zero(int* __restrict__ p, int nv) {
  int i = blockIdx.x * blockDim.x + threadIdx.x;
  if (i < nv) p[i] = 0;
}
__global__ void k_hist(const int* __restrict__ key, int* __restrict__ cnt) {
  int e = blockIdx.x * blockDim.x + threadIdx.x;
  if (e < EE_) atomicAdd(&cnt[key[e]], 1);
}
__global__ __launch_bounds__(1024) void k_scan(const int* __restrict__ cnt,
                                               int* __restrict__ rowptr,
                                               int* __restrict__ cursor) {
  __shared__ int part[1024];
  int t = threadIdx.x;
  int base = t * 32;
  int loc[32];
  int s = 0;
#pragma unroll
  for (int i = 0; i < 32; i++) { loc[i] = s; s += cnt[base + i]; }
  part[t] = s;
  __syncthreads();
  for (int off = 1; off < 1024; off <<= 1) {
    int v = (t >= off) ? part[t - off] : 0;
    __syncthreads();
    part[t] += v;
    __syncthreads();
  }
  int pre = (t == 0) ? 0 : part[t - 1];
#pragma unroll
  for (int i = 0; i < 32; i++) {
    int v = pre + loc[i];
    rowptr[base + i] = v;
    cursor[base + i] = v;
  }
  if (t == 1023) rowptr[NN_] = part[1023];
}
// fused scatter: place edge data directly at its src-sorted slot
__global__ void k_scatter(const int* __restrict__ src, const int* __restrict__ dst,
                          const float* __restrict__ ea, int* __restrict__ cursor,
                          float4* __restrict__ eas4) {
  int e = blockIdx.x * blockDim.x + threadIdx.x;
  if (e < EE_) {
    int pos = atomicAdd(&cursor[src[e]], 1);
    eas4[pos] = make_float4(ea[e * 3], ea[e * 3 + 1], ea[e * 3 + 2],
                            __int_as_float(dst[e]));
  } else if (e < EE_ + 8) {
    eas4[e] = make_float4(0.f, 0.f, 0.f, __int_as_float(0));
  }
}

// ---------------- degree-descending node order ----------------
__global__ void k_dhist(const int* __restrict__ cnt, int* __restrict__ dcnt) {
  int n = blockIdx.x * blockDim.x + threadIdx.x;
  if (n < NN_) {
    int d = cnt[n]; if (d > 255) d = 255;
    atomicAdd(&dcnt[255 - d], 1);
  }
}
__global__ void k_dscan(const int* __restrict__ dcnt, int* __restrict__ dcur) {
  __shared__ int tmp[256];
  int t = threadIdx.x;
  tmp[t] = dcnt[t];
  __syncthreads();
  int acc = 0;
  for (int i = 0; i < t; i++) acc += tmp[i];
  dcur[t] = acc;
}
__global__ void k_dscatter(const int* __restrict__ cnt, int* __restrict__ dcur,
                           int* __restrict__ norder) {
  int n = blockIdx.x * blockDim.x + threadIdx.x;
  if (n < NN_) {
    int d = cnt[n]; if (d > 255) d = 255;
    int pos = atomicAdd(&dcur[255 - d], 1);
    norder[pos] = n;
  }
}

// ---------------- per-conv kernels ----------------
// W2m lane-fast: W2m[i*1024 + j4*256 + l*4 + c] = w2[h*256 + i*16 + o],
//   h=(l>>4)*16 + j4*4 + c, o=l&15.  w1p4[h] = (w1[0..2][h], b1[h])
__global__ void k_wprep(const float* __restrict__ w2, const float* __restrict__ w1,
                        const float* __restrict__ b1, float* __restrict__ W2m,
                        float4* __restrict__ w1p4) {
  int idx = blockIdx.x * 256 + threadIdx.x;
  if (idx < 16384) {
    int i  = idx >> 10;
    int j4 = (idx >> 8) & 3;
    int l  = (idx >> 2) & 63;
    int c  = idx & 3;
    int q = l >> 4, o = l & 15;
    int h = q * 16 + j4 * 4 + c;
    W2m[idx] = w2[h * 256 + i * 16 + o];
  }
  if (idx < 64) {
    w1p4[idx] = make_float4(w1[idx], w1[64 + idx], w1[128 + idx], b1[idx]);
  }
}

// Fused per-node kernel: optional ELU on input rows, nodeinit (bias + x@root)
// into hnext, and precM (R12 body) into Mbuf. One wave per 4 nodes; elu'd x
// staged in per-wave LDS (wave-local, no barrier needed).
__global__ __launch_bounds__(256, 4) void k_node(
    const float* __restrict__ hin, const int do_elu,
    const float* __restrict__ root, const float* __restrict__ bias,
    const float* __restrict__ W2m, float* __restrict__ hnode,
    float* __restrict__ hnext, float4* __restrict__ Mbuf4) {
  __shared__ float sx[256];
  int tid = threadIdx.x;
  int wave = tid >> 6, l = tid & 63;
  int n0 = (blockIdx.x * 4 + wave) * 4;
  float* swx = &sx[wave * 64];

  // phase 1: load 4 node rows, optional elu, stash in LDS (and persist)
  float v = hin[n0 * 16 + l];
  if (do_elu) {
    v = v > 0.f ? v : expm1f(v);
    hnode[n0 * 16 + l] = v;
  }
  swx[l] = v;

  // phase 2: nodeinit — lane covers (nd = l>>4, o = l&15)
  int nd = l >> 4, o = l & 15;
  float acc = bias[o];
#pragma unroll
  for (int i = 0; i < 16; i++)
    acc = fmaf(swx[nd * 16 + i], root[i * 16 + o], acc);
  hnext[(n0 + nd) * 16 + o] = acc;

  // phase 3: precM (R12-proven body; x from LDS broadcast)
  const float4* __restrict__ W2m4 = (const float4*)W2m;
  float4 a0[4], a1[4], a2[4], a3[4];
#pragma unroll
  for (int j4 = 0; j4 < 4; j4++) {
    a0[j4] = make_float4(0.f, 0.f, 0.f, 0.f);
    a1[j4] = make_float4(0.f, 0.f, 0.f, 0.f);
    a2[j4] = make_float4(0.f, 0.f, 0.f, 0.f);
    a3[j4] = make_float4(0.f, 0.f, 0.f, 0.f);
  }
  for (int i = 0; i < 16; i++) {
    float x0 = swx[i];
    float x1 = swx[16 + i];
    float x2 = swx[32 + i];
    float x3 = swx[48 + i];
#pragma unroll
    for (int j4 = 0; j4 < 4; j4++) {
      float4 w = W2m4[i * 256 + j4 * 64 + l];
      a0[j4].x = fmaf(x0, w.x, a0[j4].x); a0[j4].y = fmaf(x0, w.y, a0[j4].y);
      a0[j4].z = fmaf(x0, w.z, a0[j4].z); a0[j4].w = fmaf(x0, w.w, a0[j4].w);
      a1[j4].x = fmaf(x1, w.x, a1[j4].x); a1[j4].y = fmaf(x1, w.y, a1[j4].y);
      a1[j4].z = fmaf(x1, w.z, a1[j4].z); a1[j4].w = fmaf(x1, w.w, a1[j4].w);
      a2[j4].x = fmaf(x2, w.x, a2[j4].x); a2[j4].y = fmaf(x2, w.y, a2[j4].y);
      a2[j4].z = fmaf(x2, w.z, a2[j4].z); a2[j4].w = fmaf(x2, w.w, a2[j4].w);
      a3[j4].x = fmaf(x3, w.x, a3[j4].x); a3[j4].y = fmaf(x3, w.y, a3[j4].y);
      a3[j4].z = fmaf(x3, w.z, a3[j4].z); a3[j4].w = fmaf(x3, w.w, a3[j4].w);
    }
  }
  int s0 = n0 * 256;
#pragma unroll
  for (int j4 = 0; j4 < 4; j4++) Mbuf4[s0 + j4 * 64 + l] = a0[j4];
#pragma unroll
  for (int j4 = 0; j4 < 4; j4++) Mbuf4[s0 + 256 + j4 * 64 + l] = a1[j4];
#pragma unroll
  for (int j4 = 0; j4 < 4; j4++) Mbuf4[s0 + 512 + j4 * 64 + l] = a2[j4];
#pragma unroll
  for (int j4 = 0; j4 < 4; j4++) Mbuf4[s0 + 768 + j4 * 64 + l] = a3[j4];
}

// Edge aggregation (R12 codegen, unchanged math). Changes: node id taken from
// degree-sorted norder; sw1 padded to 17-float4 stride so the 4 q-groups read
// from different LDS banks (R15 exposed the 4-way conflict at stride 16).
__global__ __launch_bounds__(256, 4) void k_edge(
    const float* __restrict__ hn, const int* __restrict__ rowptr,
    const float4* __restrict__ eas4, const float4* __restrict__ w1p4,
    const float* __restrict__ b2, const float4* __restrict__ Mbuf4,
    float* __restrict__ hnext, const int* __restrict__ norder) {
  __shared__ float4 sw1[4 * 17];
  int tid = threadIdx.x;
  if (tid < 64) sw1[(tid >> 4) * 17 + (tid & 15)] = w1p4[tid];
  __syncthreads();

  int wave = tid >> 6, l = tid & 63;
  int o = l & 15, q = l >> 4;
  int n = norder[blockIdx.x * 4 + wave];

  int rs = rowptr[n], re = rowptr[n + 1];
  if (rs >= re) return;

  int mb = n * 256 + l;
  float4 m0 = Mbuf4[mb], m1 = Mbuf4[mb + 64], m2 = Mbuf4[mb + 128],
         m3 = Mbuf4[mb + 192];
  float M[16] = {m0.x, m0.y, m0.z, m0.w, m1.x, m1.y, m1.z, m1.w,
                 m2.x, m2.y, m2.z, m2.w, m3.x, m3.y, m3.z, m3.w};

  const float4* __restrict__ hx4 = (const float4*)&hn[n * 16];
  float T = 0.f;
#pragma unroll
  for (int i4 = 0; i4 < 4; i4++) {
    float4 xq = hx4[i4];
    T = fmaf(xq.x, b2[(i4 * 4 + 0) * 16 + o], T);
    T = fmaf(xq.y, b2[(i4 * 4 + 1) * 16 + o], T);
    T = fmaf(xq.z, b2[(i4 * 4 + 2) * 16 + o], T);
    T = fmaf(xq.w, b2[(i4 * 4 + 3) * 16 + o], T);
  }

  const float4* __restrict__ w1v = &sw1[q * 17];

  float4 c0 = eas4[rs], c1 = eas4[rs + 1], c2 = eas4[rs + 2], c3 = eas4[rs + 3];
  for (int k = rs; k < re; k += 4) {
    float4 n0 = eas4[k + 4], n1 = eas4[k + 5], n2 = eas4[k + 6], n3 = eas4[k + 7];

    float p0 = 0.f, p1 = 0.f, p2 = 0.f, p3 = 0.f;
#pragma unroll
    for (int j = 0; j < 16; j++) {
      float4 wv = w1v[j];
      float m = M[j];
      float h0 = fmaxf(fmaf(c0.z, wv.z, fmaf(c0.y, wv.y, fmaf(c0.x, wv.x, wv.w))), 0.f);
      float h1 = fmaxf(fmaf(c1.z, wv.z, fmaf(c1.y, wv.y, fmaf(c1.x, wv.x, wv.w))), 0.f);
      float h2 = fmaxf(fmaf(c2.z, wv.z, fmaf(c2.y, wv.y, fmaf(c2.x, wv.x, wv.w))), 0.f);
      float h3 = fmaxf(fmaf(c3.z, wv.z, fmaf(c3.y, wv.y, fmaf(c3.x, wv.x, wv.w))), 0.f);
      p0 = fmaf(h0, m, p0);
      p1 = fmaf(h1, m, p1);
      p2 = fmaf(h2, m, p2);
      p3 = fmaf(h3, m, p3);
    }
    p0 += __shfl_xor(p0, 16); p1 += __shfl_xor(p1, 16);
    p2 += __shfl_xor(p2, 16); p3 += __shfl_xor(p3, 16);
    p0 += __shfl_xor(p0, 32); p1 += __shfl_xor(p1, 32);
    p2 += __shfl_xor(p2, 32); p3 += __shfl_xor(p3, 32);

    float vv  = (q == 0) ? p0   : (q == 1) ? p1   : (q == 2) ? p2   : p3;
    float dpf = (q == 0) ? c0.w : (q == 1) ? c1.w : (q == 2) ? c2.w : c3.w;
    if (k + q < re) atomicAdd(&hnext[__float_as_int(dpf) * 16 + o], vv + T);

    c0 = n0; c1 = n1; c2 = n2; c3 = n3;
  }
}

__global__ void k_elu(const float* __restrict__ in, float* __restrict__ out) {
  int idx = blockIdx.x * blockDim.x + threadIdx.x;
  if (idx >= NN_ * HC_) return;
  float v = in[idx];
  out[idx] = v > 0.f ? v : expm1f(v);
}

// ---------------- launch ----------------
extern "C" void kernel_launch(void* const* d_in, const int* in_sizes, int n_in,
                              void* d_out, int out_size, void* d_ws, size_t ws_size,
                              hipStream_t stream) {
  const float* x    = (const float*)d_in[0];
  const int*   ei   = (const int*)d_in[1];
  const float* ea   = (const float*)d_in[2];
  const float* fc2w = (const float*)d_in[3];
  const float* fc2b = (const float*)d_in[4];
  const float* fc1w = (const float*)d_in[5];
  const float* fc1b = (const float*)d_in[6];
  float* out = (float*)d_out;

  float* ws = (float*)d_ws;
  float*  h1     = ws;                               // 4096
  float*  hnode  = h1 + 4096;                        // N*16
  float*  hnext  = hnode + (size_t)NN_ * HC_;        // N*16
  float*  W2m    = hnext + (size_t)NN_ * HC_;        // 16384
  float4* w1p4   = (float4*)(W2m + 16384);           // 256 floats
  float4* eas4   = (float4*)((float*)w1p4 + 256);    // (E+8)*4 floats
  float4* Mbuf4  = (float4*)((float*)eas4 + (size_t)(EE_ + 8) * 4);  // N*1024
  int*    cnt    = (int*)((float*)Mbuf4 + (size_t)NN_ * 1024);
  int*    rowptr = cnt + NN_;                        // N+1
  int*    cursor = rowptr + NN_ + 1;                 // N
  int*    norder = cursor + NN_;                     // N
  int*    dcnt   = norder + NN_;                     // 256
  int*    dcur   = dcnt + 256;                       // 256

  const int* src  = ei;
  const int* dstp = ei + EE_;

  k_front1<<<2, 256, 0, stream>>>(x, fc2w, fc2b, h1);
  k_front2<<<1024, 512, 0, stream>>>(h1, fc1w, fc1b, hnode);

  k_zero<<<(NN_ + 255) / 256, 256, 0, stream>>>(cnt, NN_);
  k_hist<<<(EE_ + 255) / 256, 256, 0, stream>>>(src, cnt);
  k_scan<<<1, 1024, 0, stream>>>(cnt, rowptr, cursor);
  k_scatter<<<(EE_ + 8 + 255) / 256, 256, 0, stream>>>(src, dstp, ea, cursor, eas4);
  // degree-descending order
  k_zero<<<1, 256, 0, stream>>>(dcnt, 256);
  k_dhist<<<NN_ / 256, 256, 0, stream>>>(cnt, dcnt);
  k_dscan<<<1, 256, 0, stream>>>(dcnt, dcur);
  k_dscatter<<<NN_ / 256, 256, 0, stream>>>(cnt, dcur, norder);

  for (int cv = 0; cv < 2; cv++) {
    const float* root = (const float*)d_in[7 + cv * 6];
    const float* cb   = (const float*)d_in[8 + cv * 6];
    const float* w1   = (const float*)d_in[9 + cv * 6];
    const float* b1   = (const float*)d_in[10 + cv * 6];
    const float* w2   = (const float*)d_in[11 + cv * 6];
    const float* b2   = (const float*)d_in[12 + cv * 6];
    k_wprep<<<64, 256, 0, stream>>>(w2, w1, b1, W2m, w1p4);
    k_node<<<NN_ / 16, 256, 0, stream>>>(cv == 0 ? hnode : hnext, cv,
                                         root, cb, W2m, hnode, hnext, Mbuf4);
    k_edge<<<NN_ / 4, 256, 0, stream>>>(hnode, rowptr, eas4, w1p4, b2, Mbuf4,
                                        hnext, norder);
  }
  k_elu<<<NN_ * HC_ / 256, 256, 0, stream>>>(hnext, out);
}

// Round 17
// 358.781 us; speedup vs baseline: 2.9801x; 1.5259x over previous
//
#include <hip/hip_runtime.h>
#include <math.h>

#define G_   8
#define NPG_ 4096
#define HC_  16
#define LAT_ 64
#define FF_  512
#define EDIM_ 3
#define EH_  64
#define NN_  32768
#define EE_  393216

// ---------------- front-end ----------------
__global__ void k_front1(const float* __restrict__ x, const float* __restrict__ w,
                         const float* __restrict__ b, float* __restrict__ h1) {
  int c = blockIdx.x * blockDim.x + threadIdx.x;
  if (c >= FF_) return;
  float acc[G_];
#pragma unroll
  for (int g = 0; g < G_; g++) acc[g] = 0.f;
  for (int r = 0; r < LAT_; r++) {
    float wv = w[r * FF_ + c];
#pragma unroll
    for (int g = 0; g < G_; g++) acc[g] = fmaf(x[g * LAT_ + r], wv, acc[g]);
  }
#pragma unroll
  for (int g = 0; g < G_; g++) h1[g * FF_ + c] = acc[g] + b[c];
}

__global__ __launch_bounds__(512) void k_front2(const float* __restrict__ h1,
                                                const float* __restrict__ w,
                                                const float* __restrict__ b,
                                                float* __restrict__ hn) {
  __shared__ float sh[G_ * FF_];
  for (int i = threadIdx.x; i < G_ * FF_; i += blockDim.x) sh[i] = h1[i];
  __syncthreads();
  int g = threadIdx.x >> 6;
  int lane = threadIdx.x & 63;
  int c = blockIdx.x * 64 + lane;
  const float* shg = &sh[g * FF_];
  float acc = 0.f;
#pragma unroll 8
  for (int r = 0; r < FF_; r++) acc = fmaf(shg[r], w[r * (NPG_ * HC_) + c], acc);
  float v = acc + b[c];
  hn[g * (NPG_ * HC_) + c] = v > 0.f ? v : expm1f(v);
}

// ---------------- counting sort by src ----------------
__global__ void k_zero(int* __restrict__ p, int nv) {
  int i = blockIdx.x * blockDim.x + threadIdx.x;
  if (i < nv) p[i] = 0;
}
__global__ void k_hist(const int* __restrict__ key, int* __restrict__ cnt) {
  int e = blockIdx.x * blockDim.x + threadIdx.x;
  if (e < EE_) atomicAdd(&cnt[key[e]], 1);
}
__global__ __launch_bounds__(1024) void k_scan(const int* __restrict__ cnt,
                                               int* __restrict__ rowptr,
                                               int* __restrict__ cursor) {
  __shared__ int part[1024];
  int t = threadIdx.x;
  int base = t * 32;
  int loc[32];
  int s = 0;
#pragma unroll
  for (int i = 0; i < 32; i++) { loc[i] = s; s += cnt[base + i]; }
  part[t] = s;
  __syncthreads();
  for (int off = 1; off < 1024; off <<= 1) {
    int v = (t >= off) ? part[t - off] : 0;
    __syncthreads();
    part[t] += v;
    __syncthreads();
  }
  int pre = (t == 0) ? 0 : part[t - 1];
#pragma unroll
  for (int i = 0; i < 32; i++) {
    int v = pre + loc[i];
    rowptr[base + i] = v;
    cursor[base + i] = v;
  }
  if (t == 1023) rowptr[NN_] = part[1023];
}
// fused scatter: place edge data directly at its src-sorted slot
__global__ void k_scatter(const int* __restrict__ src, const int* __restrict__ dst,
                          const float* __restrict__ ea, int* __restrict__ cursor,
                          float4* __restrict__ eas4) {
  int e = blockIdx.x * blockDim.x + threadIdx.x;
  if (e < EE_) {
    int pos = atomicAdd(&cursor[src[e]], 1);
    eas4[pos] = make_float4(ea[e * 3], ea[e * 3 + 1], ea[e * 3 + 2],
                            __int_as_float(dst[e]));
  } else if (e < EE_ + 8) {
    eas4[e] = make_float4(0.f, 0.f, 0.f, __int_as_float(0));
  }
}

// ---------------- per-conv kernels ----------------
// W2m lane-fast: W2m[i*1024 + j4*256 + l*4 + c] = w2[h*256 + i*16 + o],
//   h=(l>>4)*16 + j4*4 + c, o=l&15.  w1p4[h] = (w1[0..2][h], b1[h])
__global__ void k_wprep(const float* __restrict__ w2, const float* __restrict__ w1,
                        const float* __restrict__ b1, float* __restrict__ W2m,
                        float4* __restrict__ w1p4) {
  int idx = blockIdx.x * 256 + threadIdx.x;
  if (idx < 16384) {
    int i  = idx >> 10;
    int j4 = (idx >> 8) & 3;
    int l  = (idx >> 2) & 63;
    int c  = idx & 3;
    int q = l >> 4, o = l & 15;
    int h = q * 16 + j4 * 4 + c;
    W2m[idx] = w2[h * 256 + i * 16 + o];
  }
  if (idx < 64) {
    w1p4[idx] = make_float4(w1[idx], w1[64 + idx], w1[128 + idx], b1[idx]);
  }
}

// Fused per-node kernel: optional ELU on input rows, nodeinit (bias + x@root)
// into hnext, and precM (R12 body) into Mbuf. One wave per 4 nodes; elu'd x
// staged in per-wave LDS (wave-local, no barrier needed).
__global__ __launch_bounds__(256, 4) void k_node(
    const float* __restrict__ hin, const int do_elu,
    const float* __restrict__ root, const float* __restrict__ bias,
    const float* __restrict__ W2m, float* __restrict__ hnode,
    float* __restrict__ hnext, float4* __restrict__ Mbuf4) {
  __shared__ float sx[256];
  int tid = threadIdx.x;
  int wave = tid >> 6, l = tid & 63;
  int n0 = (blockIdx.x * 4 + wave) * 4;
  float* swx = &sx[wave * 64];

  // phase 1: load 4 node rows, optional elu, stash in LDS (and persist)
  float v = hin[n0 * 16 + l];
  if (do_elu) {
    v = v > 0.f ? v : expm1f(v);
    hnode[n0 * 16 + l] = v;
  }
  swx[l] = v;

  // phase 2: nodeinit — lane covers (nd = l>>4, o = l&15)
  int nd = l >> 4, o = l & 15;
  float acc = bias[o];
#pragma unroll
  for (int i = 0; i < 16; i++)
    acc = fmaf(swx[nd * 16 + i], root[i * 16 + o], acc);
  hnext[(n0 + nd) * 16 + o] = acc;

  // phase 3: precM (R12-proven body; x from LDS broadcast)
  const float4* __restrict__ W2m4 = (const float4*)W2m;
  float4 a0[4], a1[4], a2[4], a3[4];
#pragma unroll
  for (int j4 = 0; j4 < 4; j4++) {
    a0[j4] = make_float4(0.f, 0.f, 0.f, 0.f);
    a1[j4] = make_float4(0.f, 0.f, 0.f, 0.f);
    a2[j4] = make_float4(0.f, 0.f, 0.f, 0.f);
    a3[j4] = make_float4(0.f, 0.f, 0.f, 0.f);
  }
  for (int i = 0; i < 16; i++) {
    float x0 = swx[i];
    float x1 = swx[16 + i];
    float x2 = swx[32 + i];
    float x3 = swx[48 + i];
#pragma unroll
    for (int j4 = 0; j4 < 4; j4++) {
      float4 w = W2m4[i * 256 + j4 * 64 + l];
      a0[j4].x = fmaf(x0, w.x, a0[j4].x); a0[j4].y = fmaf(x0, w.y, a0[j4].y);
      a0[j4].z = fmaf(x0, w.z, a0[j4].z); a0[j4].w = fmaf(x0, w.w, a0[j4].w);
      a1[j4].x = fmaf(x1, w.x, a1[j4].x); a1[j4].y = fmaf(x1, w.y, a1[j4].y);
      a1[j4].z = fmaf(x1, w.z, a1[j4].z); a1[j4].w = fmaf(x1, w.w, a1[j4].w);
      a2[j4].x = fmaf(x2, w.x, a2[j4].x); a2[j4].y = fmaf(x2, w.y, a2[j4].y);
      a2[j4].z = fmaf(x2, w.z, a2[j4].z); a2[j4].w = fmaf(x2, w.w, a2[j4].w);
      a3[j4].x = fmaf(x3, w.x, a3[j4].x); a3[j4].y = fmaf(x3, w.y, a3[j4].y);
      a3[j4].z = fmaf(x3, w.z, a3[j4].z); a3[j4].w = fmaf(x3, w.w, a3[j4].w);
    }
  }
  int s0 = n0 * 256;
#pragma unroll
  for (int j4 = 0; j4 < 4; j4++) Mbuf4[s0 + j4 * 64 + l] = a0[j4];
#pragma unroll
  for (int j4 = 0; j4 < 4; j4++) Mbuf4[s0 + 256 + j4 * 64 + l] = a1[j4];
#pragma unroll
  for (int j4 = 0; j4 < 4; j4++) Mbuf4[s0 + 512 + j4 * 64 + l] = a2[j4];
#pragma unroll
  for (int j4 = 0; j4 < 4; j4++) Mbuf4[s0 + 768 + j4 * 64 + l] = a3[j4];
}

// Edge aggregation (R12 codegen, natural node order). sw1 padded to stride 17
// so the 4 q-groups hit different LDS banks (R15 exposed the 4-way conflict).
__global__ __launch_bounds__(256, 4) void k_edge(
    const float* __restrict__ hn, const int* __restrict__ rowptr,
    const float4* __restrict__ eas4, const float4* __restrict__ w1p4,
    const float* __restrict__ b2, const float4* __restrict__ Mbuf4,
    float* __restrict__ hnext) {
  __shared__ float4 sw1[4 * 17];
  int tid = threadIdx.x;
  if (tid < 64) sw1[(tid >> 4) * 17 + (tid & 15)] = w1p4[tid];
  __syncthreads();

  int wave = tid >> 6, l = tid & 63;
  int o = l & 15, q = l >> 4;
  int n = blockIdx.x * 4 + wave;

  int rs = rowptr[n], re = rowptr[n + 1];
  if (rs >= re) return;

  int mb = n * 256 + l;
  float4 m0 = Mbuf4[mb], m1 = Mbuf4[mb + 64], m2 = Mbuf4[mb + 128],
         m3 = Mbuf4[mb + 192];
  float M[16] = {m0.x, m0.y, m0.z, m0.w, m1.x, m1.y, m1.z, m1.w,
                 m2.x, m2.y, m2.z, m2.w, m3.x, m3.y, m3.z, m3.w};

  const float4* __restrict__ hx4 = (const float4*)&hn[n * 16];
  float T = 0.f;
#pragma unroll
  for (int i4 = 0; i4 < 4; i4++) {
    float4 xq = hx4[i4];
    T = fmaf(xq.x, b2[(i4 * 4 + 0) * 16 + o], T);
    T = fmaf(xq.y, b2[(i4 * 4 + 1) * 16 + o], T);
    T = fmaf(xq.z, b2[(i4 * 4 + 2) * 16 + o], T);
    T = fmaf(xq.w, b2[(i4 * 4 + 3) * 16 + o], T);
  }

  const float4* __restrict__ w1v = &sw1[q * 17];

  float4 c0 = eas4[rs], c1 = eas4[rs + 1], c2 = eas4[rs + 2], c3 = eas4[rs + 3];
  for (int k = rs; k < re; k += 4) {
    float4 n0 = eas4[k + 4], n1 = eas4[k + 5], n2 = eas4[k + 6], n3 = eas4[k + 7];

    float p0 = 0.f, p1 = 0.f, p2 = 0.f, p3 = 0.f;
#pragma unroll
    for (int j = 0; j < 16; j++) {
      float4 wv = w1v[j];
      float m = M[j];
      float h0 = fmaxf(fmaf(c0.z, wv.z, fmaf(c0.y, wv.y, fmaf(c0.x, wv.x, wv.w))), 0.f);
      float h1 = fmaxf(fmaf(c1.z, wv.z, fmaf(c1.y, wv.y, fmaf(c1.x, wv.x, wv.w))), 0.f);
      float h2 = fmaxf(fmaf(c2.z, wv.z, fmaf(c2.y, wv.y, fmaf(c2.x, wv.x, wv.w))), 0.f);
      float h3 = fmaxf(fmaf(c3.z, wv.z, fmaf(c3.y, wv.y, fmaf(c3.x, wv.x, wv.w))), 0.f);
      p0 = fmaf(h0, m, p0);
      p1 = fmaf(h1, m, p1);
      p2 = fmaf(h2, m, p2);
      p3 = fmaf(h3, m, p3);
    }
    p0 += __shfl_xor(p0, 16); p1 += __shfl_xor(p1, 16);
    p2 += __shfl_xor(p2, 16); p3 += __shfl_xor(p3, 16);
    p0 += __shfl_xor(p0, 32); p1 += __shfl_xor(p1, 32);
    p2 += __shfl_xor(p2, 32); p3 += __shfl_xor(p3, 32);

    float vv  = (q == 0) ? p0   : (q == 1) ? p1   : (q == 2) ? p2   : p3;
    float dpf = (q == 0) ? c0.w : (q == 1) ? c1.w : (q == 2) ? c2.w : c3.w;
    if (k + q < re) atomicAdd(&hnext[__float_as_int(dpf) * 16 + o], vv + T);

    c0 = n0; c1 = n1; c2 = n2; c3 = n3;
  }
}

__global__ void k_elu(const float* __restrict__ in, float* __restrict__ out) {
  int idx = blockIdx.x * blockDim.x + threadIdx.x;
  if (idx >= NN_ * HC_) return;
  float v = in[idx];
  out[idx] = v > 0.f ? v : expm1f(v);
}

// ---------------- launch ----------------
extern "C" void kernel_launch(void* const* d_in, const int* in_sizes, int n_in,
                              void* d_out, int out_size, void* d_ws, size_t ws_size,
                              hipStream_t stream) {
  const float* x    = (const float*)d_in[0];
  const int*   ei   = (const int*)d_in[1];
  const float* ea   = (const float*)d_in[2];
  const float* fc2w = (const float*)d_in[3];
  const float* fc2b = (const float*)d_in[4];
  const float* fc1w = (const float*)d_in[5];
  const float* fc1b = (const float*)d_in[6];
  float* out = (float*)d_out;

  float* ws = (float*)d_ws;
  float*  h1     = ws;                               // 4096
  float*  hnode  = h1 + 4096;                        // N*16
  float*  hnext  = hnode + (size_t)NN_ * HC_;        // N*16
  float*  W2m    = hnext + (size_t)NN_ * HC_;        // 16384
  float4* w1p4   = (float4*)(W2m + 16384);           // 256 floats
  float4* eas4   = (float4*)((float*)w1p4 + 256);    // (E+8)*4 floats
  float4* Mbuf4  = (float4*)((float*)eas4 + (size_t)(EE_ + 8) * 4);  // N*1024
  int*    cnt    = (int*)((float*)Mbuf4 + (size_t)NN_ * 1024);
  int*    rowptr = cnt + NN_;                        // N+1
  int*    cursor = rowptr + NN_ + 1;                 // N

  const int* src  = ei;
  const int* dstp = ei + EE_;

  k_front1<<<2, 256, 0, stream>>>(x, fc2w, fc2b, h1);
  k_front2<<<1024, 512, 0, stream>>>(h1, fc1w, fc1b, hnode);

  k_zero<<<(NN_ + 255) / 256, 256, 0, stream>>>(cnt, NN_);
  k_hist<<<(EE_ + 255) / 256, 256, 0, stream>>>(src, cnt);
  k_scan<<<1, 1024, 0, stream>>>(cnt, rowptr, cursor);
  k_scatter<<<(EE_ + 8 + 255) / 256, 256, 0, stream>>>(src, dstp, ea, cursor, eas4);

  for (int cv = 0; cv < 2; cv++) {
    const float* root = (const float*)d_in[7 + cv * 6];
    const float* cb   = (const float*)d_in[8 + cv * 6];
    const float* w1   = (const float*)d_in[9 + cv * 6];
    const float* b1   = (const float*)d_in[10 + cv * 6];
    const float* w2   = (const float*)d_in[11 + cv * 6];
    const float* b2   = (const float*)d_in[12 + cv * 6];
    k_wprep<<<64, 256, 0, stream>>>(w2, w1, b1, W2m, w1p4);
    k_node<<<NN_ / 16, 256, 0, stream>>>(cv == 0 ? hnode : hnext, cv,
                                         root, cb, W2m, hnode, hnext, Mbuf4);
    k_edge<<<NN_ / 4, 256, 0, stream>>>(hnode, rowptr, eas4, w1p4, b2, Mbuf4,
                                        hnext);
  }
  k_elu<<<NN_ * HC_ / 256, 256, 0, stream>>>(hnext, out);
}

// Round 18
// 312.782 us; speedup vs baseline: 3.4183x; 1.1471x over previous
//
#include <hip/hip_runtime.h>
#include <math.h>

#define G_   8
#define NPG_ 4096
#define HC_  16
#define LAT_ 64
#define FF_  512
#define EDIM_ 3
#define EH_  64
#define NN_  32768
#define EE_  393216
#define EPAD_ (EE_ + NN_ * 8 + 32)   // ranges padded to multiple of 8

// ---------------- front-end ----------------
__global__ void k_front1(const float* __restrict__ x, const float* __restrict__ w,
                         const float* __restrict__ b, float* __restrict__ h1) {
  int c = blockIdx.x * blockDim.x + threadIdx.x;
  if (c >= FF_) return;
  float acc[G_];
#pragma unroll
  for (int g = 0; g < G_; g++) acc[g] = 0.f;
  for (int r = 0; r < LAT_; r++) {
    float wv = w[r * FF_ + c];
#pragma unroll
    for (int g = 0; g < G_; g++) acc[g] = fmaf(x[g * LAT_ + r], wv, acc[g]);
  }
#pragma unroll
  for (int g = 0; g < G_; g++) h1[g * FF_ + c] = acc[g] + b[c];
}

__global__ __launch_bounds__(512) void k_front2(const float* __restrict__ h1,
                                                const float* __restrict__ w,
                                                const float* __restrict__ b,
                                                float* __restrict__ hn) {
  __shared__ float sh[G_ * FF_];
  for (int i = threadIdx.x; i < G_ * FF_; i += blockDim.x) sh[i] = h1[i];
  __syncthreads();
  int g = threadIdx.x >> 6;
  int lane = threadIdx.x & 63;
  int c = blockIdx.x * 64 + lane;
  const float* shg = &sh[g * FF_];
  float acc = 0.f;
#pragma unroll 8
  for (int r = 0; r < FF_; r++) acc = fmaf(shg[r], w[r * (NPG_ * HC_) + c], acc);
  float v = acc + b[c];
  hn[g * (NPG_ * HC_) + c] = v > 0.f ? v : expm1f(v);
}

// ---------------- counting sort by src (ranges padded to mult of 8) --------
__global__ void k_zero(int* __restrict__ p, int nv) {
  int i = blockIdx.x * blockDim.x + threadIdx.x;
  if (i < nv) p[i] = 0;
}
__global__ void k_hist(const int* __restrict__ key, int* __restrict__ cnt) {
  int e = blockIdx.x * blockDim.x + threadIdx.x;
  if (e < EE_) atomicAdd(&cnt[key[e]], 1);
}
__global__ __launch_bounds__(1024) void k_scan(const int* __restrict__ cnt,
                                               int* __restrict__ rowptr,
                                               int* __restrict__ cursor) {
  __shared__ int part[1024];
  int t = threadIdx.x;
  int base = t * 32;
  int loc[32];
  int s = 0;
#pragma unroll
  for (int i = 0; i < 32; i++) {
    loc[i] = s;
    s += (cnt[base + i] + 7) & ~7;
  }
  part[t] = s;
  __syncthreads();
  for (int off = 1; off < 1024; off <<= 1) {
    int v = (t >= off) ? part[t - off] : 0;
    __syncthreads();
    part[t] += v;
    __syncthreads();
  }
  int pre = (t == 0) ? 0 : part[t - 1];
#pragma unroll
  for (int i = 0; i < 32; i++) {
    int v = pre + loc[i];
    rowptr[base + i] = v;
    cursor[base + i] = v;
  }
  if (t == 1023) rowptr[NN_] = part[1023];
}
// fused scatter: edge data directly at its (padded) src-sorted slot. Pad
// slots are never written: they hold garbage, are computed but never
// committed (k_edge guards commits with the real degree).
__global__ void k_scatter(const int* __restrict__ src, const int* __restrict__ dst,
                          const float* __restrict__ ea, int* __restrict__ cursor,
                          float4* __restrict__ eas4) {
  int e = blockIdx.x * blockDim.x + threadIdx.x;
  if (e >= EE_) return;
  int pos = atomicAdd(&cursor[src[e]], 1);
  eas4[pos] = make_float4(ea[e * 3], ea[e * 3 + 1], ea[e * 3 + 2],
                          __int_as_float(dst[e]));
}

// ---------------- per-conv kernels ----------------
// W2m lane-fast: W2m[i*1024 + j4*256 + l*4 + c] = w2[h*256 + i*16 + o],
//   h=(l>>4)*16 + j4*4 + c, o=l&15.  w1p4[h] = (w1[0..2][h], b1[h])
__global__ void k_wprep(const float* __restrict__ w2, const float* __restrict__ w1,
                        const float* __restrict__ b1, float* __restrict__ W2m,
                        float4* __restrict__ w1p4) {
  int idx = blockIdx.x * 256 + threadIdx.x;
  if (idx < 16384) {
    int i  = idx >> 10;
    int j4 = (idx >> 8) & 3;
    int l  = (idx >> 2) & 63;
    int c  = idx & 3;
    int q = l >> 4, o = l & 15;
    int h = q * 16 + j4 * 4 + c;
    W2m[idx] = w2[h * 256 + i * 16 + o];
  }
  if (idx < 64) {
    w1p4[idx] = make_float4(w1[idx], w1[64 + idx], w1[128 + idx], b1[idx]);
  }
}

// Fused per-node kernel: optional ELU, nodeinit into hnext, precM into Mbuf.
__global__ __launch_bounds__(256, 4) void k_node(
    const float* __restrict__ hin, const int do_elu,
    const float* __restrict__ root, const float* __restrict__ bias,
    const float* __restrict__ W2m, float* __restrict__ hnode,
    float* __restrict__ hnext, float4* __restrict__ Mbuf4) {
  __shared__ float sx[256];
  int tid = threadIdx.x;
  int wave = tid >> 6, l = tid & 63;
  int n0 = (blockIdx.x * 4 + wave) * 4;
  float* swx = &sx[wave * 64];

  float v = hin[n0 * 16 + l];
  if (do_elu) {
    v = v > 0.f ? v : expm1f(v);
    hnode[n0 * 16 + l] = v;
  }
  swx[l] = v;

  int nd = l >> 4, o = l & 15;
  float acc = bias[o];
#pragma unroll
  for (int i = 0; i < 16; i++)
    acc = fmaf(swx[nd * 16 + i], root[i * 16 + o], acc);
  hnext[(n0 + nd) * 16 + o] = acc;

  const float4* __restrict__ W2m4 = (const float4*)W2m;
  float4 a0[4], a1[4], a2[4], a3[4];
#pragma unroll
  for (int j4 = 0; j4 < 4; j4++) {
    a0[j4] = make_float4(0.f, 0.f, 0.f, 0.f);
    a1[j4] = make_float4(0.f, 0.f, 0.f, 0.f);
    a2[j4] = make_float4(0.f, 0.f, 0.f, 0.f);
    a3[j4] = make_float4(0.f, 0.f, 0.f, 0.f);
  }
  for (int i = 0; i < 16; i++) {
    float x0 = swx[i];
    float x1 = swx[16 + i];
    float x2 = swx[32 + i];
    float x3 = swx[48 + i];
#pragma unroll
    for (int j4 = 0; j4 < 4; j4++) {
      float4 w = W2m4[i * 256 + j4 * 64 + l];
      a0[j4].x = fmaf(x0, w.x, a0[j4].x); a0[j4].y = fmaf(x0, w.y, a0[j4].y);
      a0[j4].z = fmaf(x0, w.z, a0[j4].z); a0[j4].w = fmaf(x0, w.w, a0[j4].w);
      a1[j4].x = fmaf(x1, w.x, a1[j4].x); a1[j4].y = fmaf(x1, w.y, a1[j4].y);
      a1[j4].z = fmaf(x1, w.z, a1[j4].z); a1[j4].w = fmaf(x1, w.w, a1[j4].w);
      a2[j4].x = fmaf(x2, w.x, a2[j4].x); a2[j4].y = fmaf(x2, w.y, a2[j4].y);
      a2[j4].z = fmaf(x2, w.z, a2[j4].z); a2[j4].w = fmaf(x2, w.w, a2[j4].w);
      a3[j4].x = fmaf(x3, w.x, a3[j4].x); a3[j4].y = fmaf(x3, w.y, a3[j4].y);
      a3[j4].z = fmaf(x3, w.z, a3[j4].z); a3[j4].w = fmaf(x3, w.w, a3[j4].w);
    }
  }
  int s0 = n0 * 256;
#pragma unroll
  for (int j4 = 0; j4 < 4; j4++) Mbuf4[s0 + j4 * 64 + l] = a0[j4];
#pragma unroll
  for (int j4 = 0; j4 < 4; j4++) Mbuf4[s0 + 256 + j4 * 64 + l] = a1[j4];
#pragma unroll
  for (int j4 = 0; j4 < 4; j4++) Mbuf4[s0 + 512 + j4 * 64 + l] = a2[j4];
#pragma unroll
  for (int j4 = 0; j4 < 4; j4++) Mbuf4[s0 + 768 + j4 * 64 + l] = a3[j4];
}

// Edge aggregation, two-phase. Chunk = 8 edges.
// Phase 1: lane (es=l&7, hg=l>>3) computes hidden[h=hg*8+j], j=0..7 for edge
//          es only (hidden computed ONCE, not 16x) -> LDS hid[es*68 + h].
// Phase 2: lane (o=l&15, q=l>>4) reads each edge's q-quarter hiddens back as
//          broadcast ds_read_b128, 16 fma dot vs register M, shfl-reduce,
//          guarded atomic (pads computed but never committed).
__global__ __launch_bounds__(256, 4) void k_edge(
    const float* __restrict__ hn, const int* __restrict__ rowptr,
    const int* __restrict__ cntr, const float4* __restrict__ eas4,
    const float4* __restrict__ w1p4, const float* __restrict__ b2,
    const float4* __restrict__ Mbuf4, float* __restrict__ hnext) {
  __shared__ float4 sw1t[64];          // transposed: sw1t[j8*8+hg] = w1p4[hg*8+j8]
  __shared__ float shid[4 * 544];      // per-wave 8 edges x stride 68
  int tid = threadIdx.x;
  if (tid < 64) sw1t[(tid & 7) * 8 + (tid >> 3)] = w1p4[tid];
  __syncthreads();

  int wave = tid >> 6, l = tid & 63;
  int o = l & 15, q = l >> 4;
  int es = l & 7, hg = l >> 3;
  int n = blockIdx.x * 4 + wave;

  int deg = cntr[n];
  if (deg <= 0) return;
  int rs = rowptr[n];
  int re = rs + ((deg + 7) & ~7);
  int limit = rs + deg;

  float* __restrict__ hid = &shid[wave * 544];

  int mb = n * 256 + l;
  float4 m0 = Mbuf4[mb], m1 = Mbuf4[mb + 64], m2 = Mbuf4[mb + 128],
         m3 = Mbuf4[mb + 192];
  float M[16] = {m0.x, m0.y, m0.z, m0.w, m1.x, m1.y, m1.z, m1.w,
                 m2.x, m2.y, m2.z, m2.w, m3.x, m3.y, m3.z, m3.w};

  const float4* __restrict__ hx4 = (const float4*)&hn[n * 16];
  float T = 0.f;
#pragma unroll
  for (int i4 = 0; i4 < 4; i4++) {
    float4 xq = hx4[i4];
    T = fmaf(xq.x, b2[(i4 * 4 + 0) * 16 + o], T);
    T = fmaf(xq.y, b2[(i4 * 4 + 1) * 16 + o], T);
    T = fmaf(xq.z, b2[(i4 * 4 + 2) * 16 + o], T);
    T = fmaf(xq.w, b2[(i4 * 4 + 3) * 16 + o], T);
  }

  float4 cur = eas4[rs + es];
  for (int k = rs; k < re; k += 8) {
    float4 nxt = eas4[k + 8 + es];

    // phase 1: hidden for edge es, h = hg*8 + jj*4 + c
#pragma unroll
    for (int jj = 0; jj < 2; jj++) {
      float4 w0 = sw1t[(jj * 4 + 0) * 8 + hg];
      float4 w1q = sw1t[(jj * 4 + 1) * 8 + hg];
      float4 w2q = sw1t[(jj * 4 + 2) * 8 + hg];
      float4 w3q = sw1t[(jj * 4 + 3) * 8 + hg];
      float4 hv;
      hv.x = fmaxf(fmaf(cur.z, w0.z, fmaf(cur.y, w0.y, fmaf(cur.x, w0.x, w0.w))), 0.f);
      hv.y = fmaxf(fmaf(cur.z, w1q.z, fmaf(cur.y, w1q.y, fmaf(cur.x, w1q.x, w1q.w))), 0.f);
      hv.z = fmaxf(fmaf(cur.z, w2q.z, fmaf(cur.y, w2q.y, fmaf(cur.x, w2q.x, w2q.w))), 0.f);
      hv.w = fmaxf(fmaf(cur.z, w3q.z, fmaf(cur.y, w3q.y, fmaf(cur.x, w3q.x, w3q.w))), 0.f);
      *(float4*)&hid[es * 68 + hg * 8 + jj * 4] = hv;
    }

    // phase 2: wave-local LDS dependency, compiler orders via lgkmcnt
    float curw = cur.w;
#pragma unroll
    for (int e2 = 0; e2 < 8; e2 += 2) {
      const float4* __restrict__ ha = (const float4*)&hid[e2 * 68 + q * 16];
      const float4* __restrict__ hb = (const float4*)&hid[(e2 + 1) * 68 + q * 16];
      float4 a0 = ha[0], a1 = ha[1], a2 = ha[2], a3 = ha[3];
      float4 b0 = hb[0], b1 = hb[1], b2v = hb[2], b3 = hb[3];
      float pa = 0.f, pb = 0.f;
      pa = fmaf(a0.x, M[0], pa);  pa = fmaf(a0.y, M[1], pa);
      pa = fmaf(a0.z, M[2], pa);  pa = fmaf(a0.w, M[3], pa);
      pa = fmaf(a1.x, M[4], pa);  pa = fmaf(a1.y, M[5], pa);
      pa = fmaf(a1.z, M[6], pa);  pa = fmaf(a1.w, M[7], pa);
      pa = fmaf(a2.x, M[8], pa);  pa = fmaf(a2.y, M[9], pa);
      pa = fmaf(a2.z, M[10], pa); pa = fmaf(a2.w, M[11], pa);
      pa = fmaf(a3.x, M[12], pa); pa = fmaf(a3.y, M[13], pa);
      pa = fmaf(a3.z, M[14], pa); pa = fmaf(a3.w, M[15], pa);
      pb = fmaf(b0.x, M[0], pb);  pb = fmaf(b0.y, M[1], pb);
      pb = fmaf(b0.z, M[2], pb);  pb = fmaf(b0.w, M[3], pb);
      pb = fmaf(b1.x, M[4], pb);  pb = fmaf(b1.y, M[5], pb);
      pb = fmaf(b1.z, M[6], pb);  pb = fmaf(b1.w, M[7], pb);
      pb = fmaf(b2v.x, M[8], pb); pb = fmaf(b2v.y, M[9], pb);
      pb = fmaf(b2v.z, M[10], pb);pb = fmaf(b2v.w, M[11], pb);
      pb = fmaf(b3.x, M[12], pb); pb = fmaf(b3.y, M[13], pb);
      pb = fmaf(b3.z, M[14], pb); pb = fmaf(b3.w, M[15], pb);
      pa += __shfl_xor(pa, 16); pb += __shfl_xor(pb, 16);
      pa += __shfl_xor(pa, 32); pb += __shfl_xor(pb, 32);
      float d0 = __shfl(curw, e2);
      float d1 = __shfl(curw, e2 + 1);
      if (l < 16) {
        if (k + e2 < limit)
          atomicAdd(&hnext[__float_as_int(d0) * 16 + o], pa + T);
        if (k + e2 + 1 < limit)
          atomicAdd(&hnext[__float_as_int(d1) * 16 + o], pb + T);
      }
    }
    cur = nxt;
  }
}

__global__ void k_elu(const float* __restrict__ in, float* __restrict__ out) {
  int idx = blockIdx.x * blockDim.x + threadIdx.x;
  if (idx >= NN_ * HC_) return;
  float v = in[idx];
  out[idx] = v > 0.f ? v : expm1f(v);
}

// ---------------- launch ----------------
extern "C" void kernel_launch(void* const* d_in, const int* in_sizes, int n_in,
                              void* d_out, int out_size, void* d_ws, size_t ws_size,
                              hipStream_t stream) {
  const float* x    = (const float*)d_in[0];
  const int*   ei   = (const int*)d_in[1];
  const float* ea   = (const float*)d_in[2];
  const float* fc2w = (const float*)d_in[3];
  const float* fc2b = (const float*)d_in[4];
  const float* fc1w = (const float*)d_in[5];
  const float* fc1b = (const float*)d_in[6];
  float* out = (float*)d_out;

  float* ws = (float*)d_ws;
  float*  h1     = ws;                               // 4096
  float*  hnode  = h1 + 4096;                        // N*16
  float*  hnext  = hnode + (size_t)NN_ * HC_;        // N*16 + 16 (dummy row)
  float*  W2m    = hnext + (size_t)NN_ * HC_ + 16;   // 16384
  float4* w1p4   = (float4*)(W2m + 16384);           // 256 floats
  float4* eas4   = (float4*)((float*)w1p4 + 256);    // (EPAD_+32)*4 floats
  float4* Mbuf4  = (float4*)((float*)eas4 + (size_t)(EPAD_ + 32) * 4); // N*1024
  int*    cnt    = (int*)((float*)Mbuf4 + (size_t)NN_ * 1024);
  int*    rowptr = cnt + NN_;                        // N+1
  int*    cursor = rowptr + NN_ + 1;                 // N

  const int* src  = ei;
  const int* dstp = ei + EE_;

  k_front1<<<2, 256, 0, stream>>>(x, fc2w, fc2b, h1);
  k_front2<<<1024, 512, 0, stream>>>(h1, fc1w, fc1b, hnode);

  k_zero<<<(NN_ + 255) / 256, 256, 0, stream>>>(cnt, NN_);
  k_hist<<<(EE_ + 255) / 256, 256, 0, stream>>>(src, cnt);
  k_scan<<<1, 1024, 0, stream>>>(cnt, rowptr, cursor);
  k_scatter<<<(EE_ + 255) / 256, 256, 0, stream>>>(src, dstp, ea, cursor, eas4);

  for (int cv = 0; cv < 2; cv++) {
    const float* root = (const float*)d_in[7 + cv * 6];
    const float* cb   = (const float*)d_in[8 + cv * 6];
    const float* w1   = (const float*)d_in[9 + cv * 6];
    const float* b1   = (const float*)d_in[10 + cv * 6];
    const float* w2   = (const float*)d_in[11 + cv * 6];
    const float* b2   = (const float*)d_in[12 + cv * 6];
    k_wprep<<<64, 256, 0, stream>>>(w2, w1, b1, W2m, w1p4);
    k_node<<<NN_ / 16, 256, 0, stream>>>(cv == 0 ? hnode : hnext, cv,
                                         root, cb, W2m, hnode, hnext, Mbuf4);
    k_edge<<<NN_ / 4, 256, 0, stream>>>(hnode, rowptr, cnt, eas4, w1p4, b2,
                                        Mbuf4, hnext);
  }
  k_elu<<<NN_ * HC_ / 256, 256, 0, stream>>>(hnext, out);
}